// Round 3
// baseline (221.851 us; speedup 1.0000x reference)
//
#include <hip/hip_runtime.h>
#include <math.h>

#define NPAIR  2
#define KDIM   64
#define NKP    400
#define NPADR  448           /* keypoints padded to 14*32 */
#define DSTR   14            /* double-strips of 32 keypoint rows */
#define HWPIX  65536
#define MREF   70.0f         /* fixed softmax reference: logits = 100*cos <= 100 */

/* ws layout (dwords):
   [0, AFRAG_DW)  : tgt A-fragments [p][d][rt][ks][hi/lo][lane][4dw], bf16 pairs
   [AFRAG_DW, ..) : partials [p][448][256] float2 {S, U_local}            */
#define AFRAG_DW (NPAIR*DSTR*2*2*2*256)   /* 57344 dwords */

using frag_ab = __attribute__((ext_vector_type(8))) short;   // 8 bf16
using f32x4   = __attribute__((ext_vector_type(4))) float;

__device__ __forceinline__ unsigned short f2bf(float f){
    unsigned u = __builtin_bit_cast(unsigned, f);
    u += 0x7fffu + ((u >> 16) & 1u);          // round-to-nearest-even
    return (unsigned short)(u >> 16);
}
__device__ __forceinline__ float bf2f(unsigned short h){
    unsigned u = ((unsigned)h) << 16;
    return __builtin_bit_cast(float, u);
}
/* butterfly sum over 16-lane row groups, pure VALU (DPP) */
__device__ __forceinline__ float red16(float v){
    v += __builtin_bit_cast(float, __builtin_amdgcn_update_dpp(0, __builtin_bit_cast(int, v), 0xB1,  0xF, 0xF, true)); // xor1
    v += __builtin_bit_cast(float, __builtin_amdgcn_update_dpp(0, __builtin_bit_cast(int, v), 0x4E,  0xF, 0xF, true)); // xor2
    v += __builtin_bit_cast(float, __builtin_amdgcn_update_dpp(0, __builtin_bit_cast(int, v), 0x141, 0xF, 0xF, true)); // half-mirror
    v += __builtin_bit_cast(float, __builtin_amdgcn_update_dpp(0, __builtin_bit_cast(int, v), 0x140, 0xF, 0xF, true)); // mirror
    return v;
}

/* normalize tgt desc, split to bf16 hi/lo, store in MFMA A-frag order.
   Coalesced: stage the [64c][32n] strip via LDS first. */
__global__ __launch_bounds__(256) void prep_kernel(
    const float* __restrict__ ksc, const float* __restrict__ kd,
    const int* __restrict__ tgt_ids, const int* __restrict__ src_ids,
    unsigned* __restrict__ wsu, float* __restrict__ out)
{
    __shared__ float xs[KDIM][33];
    __shared__ float inv_s[32];
    int d = blockIdx.x, p = blockIdx.y, t = threadIdx.x;
    int tgt = tgt_ids[p];
    int nl = t & 31, c0 = t >> 5;
    #pragma unroll
    for (int cc = 0; cc < 8; ++cc){
        int c = cc*8 + c0;
        int n = d*32 + nl;
        xs[c][nl] = (n < NKP) ? kd[(tgt*KDIM + c)*NKP + n] : 0.f;
    }
    __syncthreads();
    if (t < 32){
        float s = 0.f;
        #pragma unroll
        for (int c = 0; c < KDIM; ++c){ float v = xs[c][t]; s = fmaf(v, v, s); }
        inv_s[t] = 1.f / fmaxf(sqrtf(s), 1e-12f);
    }
    __syncthreads();
    {
        int l = t & 63, rk = t >> 6;
        int rt = rk >> 1, ks = rk & 1;
        int cl = l & 15, g = l >> 4;
        int nloc = rt*16 + cl;
        float inv = inv_s[nloc];
        int k0 = ks*32 + g*8;
        unsigned hu[4], lu[4];
        #pragma unroll
        for (int j2 = 0; j2 < 4; ++j2){
            float xa = xs[k0 + 2*j2    ][nloc] * inv;
            float xb = xs[k0 + 2*j2 + 1][nloc] * inv;
            unsigned short ha = f2bf(xa), hb = f2bf(xb);
            unsigned short la = f2bf(xa - bf2f(ha)), lb = f2bf(xb - bf2f(hb));
            hu[j2] = (unsigned)ha | ((unsigned)hb << 16);
            lu[j2] = (unsigned)la | ((unsigned)lb << 16);
        }
        unsigned base = (unsigned)((((p*DSTR + d)*2 + rt)*2 + ks)*2)*256 + l*4;
        *(uint4*)&wsu[base]       = make_uint4(hu[0], hu[1], hu[2], hu[3]);
        *(uint4*)&wsu[base + 256] = make_uint4(lu[0], lu[1], lu[2], lu[3]);
    }
    if (t < 32){
        int n = d*32 + t;
        if (n < NKP) out[NPAIR*NKP*2 + p*NKP + n] = ksc[tgt*NKP + n];
    }
    if (d == 0 && t == 0){
        out[NPAIR*NKP*3 + p]         = (float)tgt;
        out[NPAIR*NKP*3 + NPAIR + p] = (float)src_ids[p];
    }
}

/* one block per (pair, image row of 256 px). Single-pass streaming staging
   (raw bf16 split, norm deferred to epilogue), barrier-free split-bf16 MFMA
   main loop, fixed-ref softmax partials. */
__global__ __launch_bounds__(256, 2) void match_kernel(
    const float* __restrict__ dd, const int* __restrict__ src_ids,
    const unsigned* __restrict__ wsu, float* __restrict__ part)
{
    __shared__ unsigned lds[16384];   // hi plane [0,8192) dw, lo plane [8192,16384)
    __shared__ float invn_s[256];
    int mb = blockIdx.x, p = blockIdx.y, t = threadIdx.x;
    const float* plane = dd + (size_t)src_ids[p]*KDIM*HWPIX + mb*256;

    /* staging: thread t owns pixel column m=t; stream 8 floats at a time:
       split RAW values to bf16 hi/lo (no norm yet), accumulate sum-sq. */
    {
        int m = t;
        unsigned sw7 = (unsigned)(m & 7) << 2;
        float ssum = 0.f;
        #pragma unroll
        for (int s2 = 0; s2 < 8; ++s2){
            float v[8];
            #pragma unroll
            for (int j = 0; j < 8; ++j) v[j] = plane[(size_t)(s2*8 + j)*HWPIX + m];
            unsigned hq[4], lq[4];
            #pragma unroll
            for (int q = 0; q < 4; ++q){
                float a = v[2*q], b = v[2*q + 1];
                ssum = fmaf(a, a, ssum);
                ssum = fmaf(b, b, ssum);
                unsigned short ha = f2bf(a), hb = f2bf(b);
                unsigned short la = f2bf(a - bf2f(ha)), lb = f2bf(b - bf2f(hb));
                hq[q] = (unsigned)ha | ((unsigned)hb << 16);
                lq[q] = (unsigned)la | ((unsigned)lb << 16);
            }
            unsigned dwb = (unsigned)m*32 + (((unsigned)s2 << 2) ^ sw7);
            *(uint4*)&lds[dwb]        = make_uint4(hq[0], hq[1], hq[2], hq[3]);
            *(uint4*)&lds[8192 + dwb] = make_uint4(lq[0], lq[1], lq[2], lq[3]);
        }
        invn_s[m] = 100.f / fmaxf(sqrtf(ssum), 1e-12f);   // temp folded here
    }
    __syncthreads();   // only barrier; main loop is barrier-free

    int w = t >> 6, l = t & 63;
    int cl = l & 15, g = l >> 4;
    float invm[16];
    #pragma unroll
    for (int mt = 0; mt < 16; ++mt) invm[mt] = invn_s[mt*16 + cl];

    for (int d = w; d < DSTR; d += 4){
        uint4 AH[2][2], AL[2][2];
        #pragma unroll
        for (int rt = 0; rt < 2; ++rt)
        #pragma unroll
        for (int ks = 0; ks < 2; ++ks){
            unsigned base = (unsigned)((((p*DSTR + d)*2 + rt)*2 + ks)*2)*256 + l*4;
            AH[rt][ks] = *(const uint4*)&wsu[base];
            AL[rt][ks] = *(const uint4*)&wsu[base + 256];
        }
        f32x4 acc[2][16];
        #pragma unroll
        for (int rt = 0; rt < 2; ++rt)
            #pragma unroll
            for (int mt = 0; mt < 16; ++mt)
                acc[rt][mt] = (f32x4){0.f, 0.f, 0.f, 0.f};

        #pragma unroll
        for (int mt = 0; mt < 16; ++mt){
            int mrow = mt*16 + cl;
            unsigned swm = (unsigned)(mrow & 7) << 2;
            #pragma unroll
            for (int ks = 0; ks < 2; ++ks){
                unsigned dwb = (unsigned)mrow*32 + (((unsigned)(ks*4 + g) << 2) ^ swm);
                frag_ab BH = __builtin_bit_cast(frag_ab, *(const uint4*)&lds[dwb]);
                frag_ab BL = __builtin_bit_cast(frag_ab, *(const uint4*)&lds[8192 + dwb]);
                frag_ab aH0 = __builtin_bit_cast(frag_ab, AH[0][ks]);
                frag_ab aH1 = __builtin_bit_cast(frag_ab, AH[1][ks]);
                frag_ab aL0 = __builtin_bit_cast(frag_ab, AL[0][ks]);
                frag_ab aL1 = __builtin_bit_cast(frag_ab, AL[1][ks]);
                acc[0][mt] = __builtin_amdgcn_mfma_f32_16x16x32_bf16(aH0, BH, acc[0][mt], 0, 0, 0);
                acc[1][mt] = __builtin_amdgcn_mfma_f32_16x16x32_bf16(aH1, BH, acc[1][mt], 0, 0, 0);
                acc[0][mt] = __builtin_amdgcn_mfma_f32_16x16x32_bf16(aH0, BL, acc[0][mt], 0, 0, 0);
                acc[1][mt] = __builtin_amdgcn_mfma_f32_16x16x32_bf16(aH1, BL, acc[1][mt], 0, 0, 0);
                acc[0][mt] = __builtin_amdgcn_mfma_f32_16x16x32_bf16(aL0, BH, acc[0][mt], 0, 0, 0);
                acc[1][mt] = __builtin_amdgcn_mfma_f32_16x16x32_bf16(aL1, BH, acc[1][mt], 0, 0, 0);
            }
        }
        /* fixed-ref softmax partials; per-pixel norm applied here */
        #pragma unroll
        for (int rt = 0; rt < 2; ++rt)
        #pragma unroll
        for (int r = 0; r < 4; ++r){
            float sE = 0.f, sU = 0.f;
            #pragma unroll
            for (int mt = 0; mt < 16; ++mt){
                float e = __expf(fmaf(acc[rt][mt][r], invm[mt], -MREF));
                sE += e;
                sU = fmaf(e, (float)(mt*16), sU);
            }
            sU = fmaf((float)cl, sE, sU);
            sE = red16(sE); sU = red16(sU);
            if (cl == 0){
                int n = d*32 + rt*16 + g*4 + r;
                *(float2*)&part[((size_t)(p*NPADR + n)*256 + mb)*2] = make_float2(sE, sU);
            }
        }
    }
}

/* one wave per (p,n): coalesced float4 partial reads, pure sum (fixed ref) */
__global__ __launch_bounds__(256) void merge_kernel(
    const float* __restrict__ part, float* __restrict__ out)
{
    int wid = blockIdx.x*4 + (threadIdx.x >> 6);   // 0..799
    int l = threadIdx.x & 63;
    int p = wid / NKP, n = wid - p*NKP;
    const float* base = part + (size_t)(p*NPADR + n)*512;
    float4 q0 = *(const float4*)&base[4*l];          // mb = 2l, 2l+1
    float4 q1 = *(const float4*)&base[256 + 4*l];    // mb = 128+2l, 129+2l
    float S = q0.x + q0.z + q1.x + q1.z;
    float U = q0.y + q0.w + q1.y + q1.w;
    float V = (float)(2*l)*q0.x + (float)(2*l+1)*q0.z
            + (float)(128+2*l)*q1.x + (float)(129+2*l)*q1.z;
    #pragma unroll
    for (int off = 1; off < 64; off <<= 1){
        S += __shfl_xor(S, off);
        U += __shfl_xor(U, off);
        V += __shfl_xor(V, off);
    }
    if (l == 0){
        out[(p*NKP + n)*2 + 0] = U / S;
        out[(p*NKP + n)*2 + 1] = V / S;
    }
}

extern "C" void kernel_launch(void* const* d_in, const int* in_sizes, int n_in,
                              void* d_out, int out_size, void* d_ws, size_t ws_size,
                              hipStream_t stream)
{
    const float* ksc     = (const float*)d_in[0];  // keypoint_scores [4,1,400]
    const float* kd      = (const float*)d_in[1];  // keypoint_desc  [4,64,400]
    const float* dd      = (const float*)d_in[2];  // desc_dense     [4,64,256,256]
    const int*   tgt_ids = (const int*)d_in[3];
    const int*   src_ids = (const int*)d_in[4];
    float* out = (float*)d_out;
    unsigned* wsu = (unsigned*)d_ws;
    float* part = (float*)d_ws + AFRAG_DW;

    prep_kernel <<<dim3(DSTR, NPAIR), 256, 0, stream>>>(ksc, kd, tgt_ids, src_ids, wsu, out);
    match_kernel<<<dim3(256,  NPAIR), 256, 0, stream>>>(dd, src_ids, wsu, part);
    merge_kernel<<<200,               256, 0, stream>>>(part, out);
}

// Round 4
// 130.976 us; speedup vs baseline: 1.6938x; 1.6938x over previous
//
#include <hip/hip_runtime.h>
#include <math.h>

#define NPAIR  2
#define KDIM   64
#define NKP    400
#define NPADR  448           /* keypoints padded to 14*32 */
#define DSTR   14            /* double-strips of 32 keypoint rows */
#define HWPIX  65536
#define MREF   70.0f         /* fixed softmax reference: logits = 100*cos <= 100 */

/* ws layout (dwords):
   [0, AFRAG_DW)  : tgt A-fragments [p][d][rt][ks][hi/lo][lane][4dw], bf16 pairs
   [AFRAG_DW, ..) : partials [p][448][256 mb][2 half] float2 {S, U_local} */
#define AFRAG_DW (NPAIR*DSTR*2*2*2*256)   /* 57344 dwords */

using frag_ab = __attribute__((ext_vector_type(8))) short;   // 8 bf16
using f32x4   = __attribute__((ext_vector_type(4))) float;

__device__ __forceinline__ unsigned short f2bf(float f){
    unsigned u = __builtin_bit_cast(unsigned, f);
    u += 0x7fffu + ((u >> 16) & 1u);          // round-to-nearest-even
    return (unsigned short)(u >> 16);
}
__device__ __forceinline__ float bf2f(unsigned short h){
    unsigned u = ((unsigned)h) << 16;
    return __builtin_bit_cast(float, u);
}
/* butterfly sum over 16-lane row groups, pure VALU (DPP) */
__device__ __forceinline__ float red16(float v){
    v += __builtin_bit_cast(float, __builtin_amdgcn_update_dpp(0, __builtin_bit_cast(int, v), 0xB1,  0xF, 0xF, true)); // xor1
    v += __builtin_bit_cast(float, __builtin_amdgcn_update_dpp(0, __builtin_bit_cast(int, v), 0x4E,  0xF, 0xF, true)); // xor2
    v += __builtin_bit_cast(float, __builtin_amdgcn_update_dpp(0, __builtin_bit_cast(int, v), 0x141, 0xF, 0xF, true)); // half-mirror
    v += __builtin_bit_cast(float, __builtin_amdgcn_update_dpp(0, __builtin_bit_cast(int, v), 0x140, 0xF, 0xF, true)); // mirror
    return v;
}

/* normalize tgt desc, split to bf16 hi/lo, store in MFMA A-frag order.
   Coalesced: stage the [64c][32n] strip via LDS first. */
__global__ __launch_bounds__(256) void prep_kernel(
    const float* __restrict__ ksc, const float* __restrict__ kd,
    const int* __restrict__ tgt_ids, const int* __restrict__ src_ids,
    unsigned* __restrict__ wsu, float* __restrict__ out)
{
    __shared__ float xs[KDIM][33];
    __shared__ float inv_s[32];
    int d = blockIdx.x, p = blockIdx.y, t = threadIdx.x;
    int tgt = tgt_ids[p];
    int nl = t & 31, c0 = t >> 5;
    #pragma unroll
    for (int cc = 0; cc < 8; ++cc){
        int c = cc*8 + c0;
        int n = d*32 + nl;
        xs[c][nl] = (n < NKP) ? kd[(tgt*KDIM + c)*NKP + n] : 0.f;
    }
    __syncthreads();
    if (t < 32){
        float s = 0.f;
        #pragma unroll
        for (int c = 0; c < KDIM; ++c){ float v = xs[c][t]; s = fmaf(v, v, s); }
        inv_s[t] = 1.f / fmaxf(sqrtf(s), 1e-12f);
    }
    __syncthreads();
    {
        int l = t & 63, rk = t >> 6;
        int rt = rk >> 1, ks = rk & 1;
        int cl = l & 15, g = l >> 4;
        int nloc = rt*16 + cl;
        float inv = inv_s[nloc];
        int k0 = ks*32 + g*8;
        unsigned hu[4], lu[4];
        #pragma unroll
        for (int j2 = 0; j2 < 4; ++j2){
            float xa = xs[k0 + 2*j2    ][nloc] * inv;
            float xb = xs[k0 + 2*j2 + 1][nloc] * inv;
            unsigned short ha = f2bf(xa), hb = f2bf(xb);
            unsigned short la = f2bf(xa - bf2f(ha)), lb = f2bf(xb - bf2f(hb));
            hu[j2] = (unsigned)ha | ((unsigned)hb << 16);
            lu[j2] = (unsigned)la | ((unsigned)lb << 16);
        }
        unsigned base = (unsigned)((((p*DSTR + d)*2 + rt)*2 + ks)*2)*256 + l*4;
        *(uint4*)&wsu[base]       = make_uint4(hu[0], hu[1], hu[2], hu[3]);
        *(uint4*)&wsu[base + 256] = make_uint4(lu[0], lu[1], lu[2], lu[3]);
    }
    if (t < 32){
        int n = d*32 + t;
        if (n < NKP) out[NPAIR*NKP*2 + p*NKP + n] = ksc[tgt*NKP + n];
    }
    if (d == 0 && t == 0){
        out[NPAIR*NKP*3 + p]         = (float)tgt;
        out[NPAIR*NKP*3 + NPAIR + p] = (float)src_ids[p];
    }
}

/* one block per (pair, image row of 256 px). Streaming staging (raw bf16
   split, norm deferred), then each wave owns a 128-pixel half and 7 of 14
   keypoint double-strips: acc[2][8] = 64 regs, no spill. */
__global__ __launch_bounds__(256, 2) void match_kernel(
    const float* __restrict__ dd, const int* __restrict__ src_ids,
    const unsigned* __restrict__ wsu, float* __restrict__ part)
{
    __shared__ unsigned lds[16384];   // hi plane [0,8192) dw, lo plane [8192,16384)
    __shared__ float invn_s[256];
    int mb = blockIdx.x, p = blockIdx.y, t = threadIdx.x;
    const float* plane = dd + (size_t)src_ids[p]*KDIM*HWPIX + mb*256;

    /* staging: thread t owns pixel column m=t; stream 8 floats at a time:
       split RAW values to bf16 hi/lo (no norm yet), accumulate sum-sq. */
    {
        int m = t;
        unsigned sw7 = (unsigned)(m & 7) << 2;
        float ssum = 0.f;
        #pragma unroll
        for (int s2 = 0; s2 < 8; ++s2){
            float v[8];
            #pragma unroll
            for (int j = 0; j < 8; ++j) v[j] = plane[(size_t)(s2*8 + j)*HWPIX + m];
            unsigned hq[4], lq[4];
            #pragma unroll
            for (int q = 0; q < 4; ++q){
                float a = v[2*q], b = v[2*q + 1];
                ssum = fmaf(a, a, ssum);
                ssum = fmaf(b, b, ssum);
                unsigned short ha = f2bf(a), hb = f2bf(b);
                unsigned short la = f2bf(a - bf2f(ha)), lb = f2bf(b - bf2f(hb));
                hq[q] = (unsigned)ha | ((unsigned)hb << 16);
                lq[q] = (unsigned)la | ((unsigned)lb << 16);
            }
            unsigned dwb = (unsigned)m*32 + (((unsigned)s2 << 2) ^ sw7);
            *(uint4*)&lds[dwb]        = make_uint4(hq[0], hq[1], hq[2], hq[3]);
            *(uint4*)&lds[8192 + dwb] = make_uint4(lq[0], lq[1], lq[2], lq[3]);
        }
        invn_s[m] = 100.f / fmaxf(sqrtf(ssum), 1e-12f);   // temp folded here
    }
    __syncthreads();   // only barrier; main loop is barrier-free

    int w = t >> 6, l = t & 63;
    int cl = l & 15, g = l >> 4;
    int mhalf = w & 1;           // which 128-pixel half this wave owns
    int mtb = mhalf << 3;        // first 16-px tile index
    float invm[8];
    #pragma unroll
    for (int mi = 0; mi < 8; ++mi) invm[mi] = invn_s[(mtb + mi)*16 + cl];

    #pragma unroll 1             /* forbid unroll: keeps one acc set live */
    for (int d = (w >> 1); d < DSTR; d += 2){
        f32x4 acc[2][8];
        #pragma unroll
        for (int rt = 0; rt < 2; ++rt)
            #pragma unroll
            for (int mi = 0; mi < 8; ++mi)
                acc[rt][mi] = (f32x4){0.f, 0.f, 0.f, 0.f};

        #pragma unroll
        for (int ks = 0; ks < 2; ++ks){
            unsigned base0 = (unsigned)((((p*DSTR + d)*2 + 0)*2 + ks)*2)*256 + l*4;
            unsigned base1 = (unsigned)((((p*DSTR + d)*2 + 1)*2 + ks)*2)*256 + l*4;
            frag_ab aH0 = __builtin_bit_cast(frag_ab, *(const uint4*)&wsu[base0]);
            frag_ab aL0 = __builtin_bit_cast(frag_ab, *(const uint4*)&wsu[base0 + 256]);
            frag_ab aH1 = __builtin_bit_cast(frag_ab, *(const uint4*)&wsu[base1]);
            frag_ab aL1 = __builtin_bit_cast(frag_ab, *(const uint4*)&wsu[base1 + 256]);
            #pragma unroll
            for (int mi = 0; mi < 8; ++mi){
                int mrow = (mtb + mi)*16 + cl;
                unsigned swm = (unsigned)(mrow & 7) << 2;
                unsigned dwb = (unsigned)mrow*32 + (((unsigned)(ks*4 + g) << 2) ^ swm);
                frag_ab BH = __builtin_bit_cast(frag_ab, *(const uint4*)&lds[dwb]);
                frag_ab BL = __builtin_bit_cast(frag_ab, *(const uint4*)&lds[8192 + dwb]);
                acc[0][mi] = __builtin_amdgcn_mfma_f32_16x16x32_bf16(aH0, BH, acc[0][mi], 0, 0, 0);
                acc[1][mi] = __builtin_amdgcn_mfma_f32_16x16x32_bf16(aH1, BH, acc[1][mi], 0, 0, 0);
                acc[0][mi] = __builtin_amdgcn_mfma_f32_16x16x32_bf16(aH0, BL, acc[0][mi], 0, 0, 0);
                acc[1][mi] = __builtin_amdgcn_mfma_f32_16x16x32_bf16(aH1, BL, acc[1][mi], 0, 0, 0);
                acc[0][mi] = __builtin_amdgcn_mfma_f32_16x16x32_bf16(aL0, BH, acc[0][mi], 0, 0, 0);
                acc[1][mi] = __builtin_amdgcn_mfma_f32_16x16x32_bf16(aL1, BH, acc[1][mi], 0, 0, 0);
            }
        }
        /* fixed-ref softmax partials; per-pixel norm applied here */
        #pragma unroll
        for (int rt = 0; rt < 2; ++rt)
        #pragma unroll
        for (int r = 0; r < 4; ++r){
            float sE = 0.f, sU = 0.f;
            #pragma unroll
            for (int mi = 0; mi < 8; ++mi){
                float e = __expf(fmaf(acc[rt][mi][r], invm[mi], -MREF));
                sE += e;
                sU = fmaf(e, (float)((mtb + mi)*16), sU);
            }
            sU = fmaf((float)cl, sE, sU);
            sE = red16(sE); sU = red16(sU);
            if (cl == 0){
                int n = d*32 + rt*16 + g*4 + r;
                *(float2*)&part[(((size_t)(p*NPADR + n)*256 + mb)*2 + mhalf)*2] =
                    make_float2(sE, sU);
            }
        }
    }
}

/* one wave per (p,n): coalesced float4 partial reads, pure sum (fixed ref) */
__global__ __launch_bounds__(256) void merge_kernel(
    const float* __restrict__ part, float* __restrict__ out)
{
    int wid = blockIdx.x*4 + (threadIdx.x >> 6);   // 0..799
    int l = threadIdx.x & 63;
    int p = wid / NKP, n = wid - p*NKP;
    const float* base = part + (size_t)(p*NPADR + n)*1024;  // 256 mb * 2 half * 2 f
    float S = 0.f, U = 0.f, V = 0.f;
    #pragma unroll
    for (int k4 = 0; k4 < 4; ++k4){
        int mbk = l + 64*k4;
        float4 q = *(const float4*)&base[mbk*4];   // both halves of row mbk
        float s = q.x + q.z;
        S += s;
        U += q.y + q.w;
        V = fmaf((float)mbk, s, V);
    }
    #pragma unroll
    for (int off = 1; off < 64; off <<= 1){
        S += __shfl_xor(S, off);
        U += __shfl_xor(U, off);
        V += __shfl_xor(V, off);
    }
    if (l == 0){
        out[(p*NKP + n)*2 + 0] = U / S;
        out[(p*NKP + n)*2 + 1] = V / S;
    }
}

extern "C" void kernel_launch(void* const* d_in, const int* in_sizes, int n_in,
                              void* d_out, int out_size, void* d_ws, size_t ws_size,
                              hipStream_t stream)
{
    const float* ksc     = (const float*)d_in[0];  // keypoint_scores [4,1,400]
    const float* kd      = (const float*)d_in[1];  // keypoint_desc  [4,64,400]
    const float* dd      = (const float*)d_in[2];  // desc_dense     [4,64,256,256]
    const int*   tgt_ids = (const int*)d_in[3];
    const int*   src_ids = (const int*)d_in[4];
    float* out = (float*)d_out;
    unsigned* wsu = (unsigned*)d_ws;
    float* part = (float*)d_ws + AFRAG_DW;

    prep_kernel <<<dim3(DSTR, NPAIR), 256, 0, stream>>>(ksc, kd, tgt_ids, src_ids, wsu, out);
    match_kernel<<<dim3(256,  NPAIR), 256, 0, stream>>>(dd, src_ids, wsu, part);
    merge_kernel<<<200,               256, 0, stream>>>(part, out);
}